// Round 1
// baseline (387.374 us; speedup 1.0000x reference)
//
#include <hip/hip_runtime.h>
#include <hip/hip_bf16.h>

// Problem constants: N=2, L=2048, S=2048, D=128, H=32
#define N_B 2
#define L_Q 2048
#define S_S 2048
#define D_D 128
#define H_H 32
// 1/sqrt(128) * log2(e), folded into K projection so attn uses exp2 directly
#define SCALEK (0.08838834764831845f * 1.4426950408889634f)

typedef __attribute__((ext_vector_type(8))) short bf8;   // 8 bf16 (4 VGPR)
typedef __attribute__((ext_vector_type(4))) float f4;    // 4 f32

#define MFMA(a, b, c) __builtin_amdgcn_mfma_f32_16x16x32_bf16(a, b, c, 0, 0, 0)

__device__ __forceinline__ short f2bf(float x) {
    union { float f; unsigned u; } v; v.f = x;
    unsigned r = v.u + 0x7FFFu + ((v.u >> 16) & 1u);   // RNE
    return (short)(r >> 16);
}

// 8 consecutive f32 from global -> bf16x8 fragment
__device__ __forceinline__ bf8 load8(const float* p) {
    const float4* q = (const float4*)p;
    float4 a = q[0], b = q[1];
    bf8 r;
    r[0] = f2bf(a.x); r[1] = f2bf(a.y); r[2] = f2bf(a.z); r[3] = f2bf(a.w);
    r[4] = f2bf(b.x); r[5] = f2bf(b.y); r[6] = f2bf(b.z); r[7] = f2bf(b.w);
    return r;
}

// async global->LDS, 16B per lane. lds dst must be wave-uniform base (+lane*16 implicit)
__device__ __forceinline__ void async16(const void* g, void* l) {
    __builtin_amdgcn_global_load_lds(
        (const __attribute__((address_space(1))) unsigned*)g,
        (__attribute__((address_space(3))) unsigned*)l, 16, 0, 0);
}

// ---------------- Kernel A: Wc [4096][128] f32 -> WcT [128][4096] bf16 ----------------
__global__ __launch_bounds__(256) void k_wct(const float* __restrict__ Wc,
                                             unsigned short* __restrict__ WcT) {
    int idx = blockIdx.x * 256 + threadIdx.x;   // 524288 total
    int n = idx >> 12;          // 0..127
    int k = idx & 4095;         // 0..4095
    WcT[idx] = (unsigned short)f2bf(Wc[k * D_D + n]);
}

// ---------------- Kernel B: K/V projections ----------------
// job 0: Kb[n][h][s][d]  = (states@Wk + bk) * SCALEK   (bf16, row-major in d)
// job 1: VTb[n][h][d][s] = (states@Wv + bv)            (bf16, transposed)
__global__ __launch_bounds__(256) void k_proj(const float* __restrict__ states,
        const float* __restrict__ Wk, const float* __restrict__ bk,
        const float* __restrict__ Wv, const float* __restrict__ bv,
        unsigned short* __restrict__ Kb, unsigned short* __restrict__ VTb) {
    __shared__ unsigned short WT[128 * 128];    // W^T bf16, swizzled, 32KB
    const int tid = threadIdx.x;
    const int l = tid & 63, w = tid >> 6;
    const int lrow = l & 15, lgrp = l >> 4;
    const int bx = blockIdx.x;                  // (n*H + h)*32 + sc
    const int sc = bx & 31;
    const int nh = bx >> 5;
    const int h = nh & 31, n = nh >> 5;
    const int job = blockIdx.y;

    const float* W = (job ? Wv : Wk) + (size_t)h * (D_D * D_D);
    char* WTc = (char*)WT;
    // stage W^T: coalesced f32 reads, swizzled bf16 LDS writes (WT[d][k], swz byte^((d&7)<<4))
    #pragma unroll
    for (int i = 0; i < 64; ++i) {
        int flat = i * 256 + tid;               // = k*128 + d
        int k = flat >> 7, d = flat & 127;
        short val = f2bf(W[flat]);
        int off = d * 256 + ((k * 2) ^ ((d & 7) << 4));
        *(short*)(WTc + off) = val;
    }
    __syncthreads();

    if (job == 0) {
        // M = 16 s-rows per wave, N = 128 d
        const float* srow = states + ((size_t)n * S_S + sc * 64 + w * 16 + lrow) * D_D;
        bf8 a[4];
        #pragma unroll
        for (int t = 0; t < 4; ++t) a[t] = load8(srow + t * 32 + lgrp * 8);
        f4 acc[8];
        #pragma unroll
        for (int i = 0; i < 8; ++i) acc[i] = (f4)(0.f);
        #pragma unroll
        for (int nf = 0; nf < 8; ++nf) {
            int drow = nf * 16 + lrow;          // B-frag n-index = d
            int swz = (drow & 7) << 4;
            #pragma unroll
            for (int t = 0; t < 4; ++t) {
                bf8 b = *(const bf8*)(WTc + drow * 256 + (((t * 32 + lgrp * 8) * 2) ^ swz));
                acc[nf] = MFMA(a[t], b, acc[nf]);
            }
        }
        unsigned short* Kout = Kb + (size_t)(n * H_H + h) * S_S * D_D;
        #pragma unroll
        for (int nf = 0; nf < 8; ++nf) {
            int dcol = nf * 16 + lrow;
            float bias = bk[h * D_D + dcol];
            #pragma unroll
            for (int r = 0; r < 4; ++r) {
                int srw = sc * 64 + w * 16 + lgrp * 4 + r;
                Kout[(size_t)srw * D_D + dcol] = (unsigned short)f2bf((acc[nf][r] + bias) * SCALEK);
            }
        }
    } else {
        // V^T: M = d (32 rows per wave), N = 64 s. A = Wv^T (from LDS), B = states^T (global)
        bf8 a[2][4];
        #pragma unroll
        for (int mf = 0; mf < 2; ++mf) {
            int drow = w * 32 + mf * 16 + lrow;
            int swz = (drow & 7) << 4;
            #pragma unroll
            for (int t = 0; t < 4; ++t)
                a[mf][t] = *(const bf8*)(WTc + drow * 256 + (((t * 32 + lgrp * 8) * 2) ^ swz));
        }
        f4 acc[2][4];
        #pragma unroll
        for (int mf = 0; mf < 2; ++mf)
            #pragma unroll
            for (int nf = 0; nf < 4; ++nf) acc[mf][nf] = (f4)(0.f);
        #pragma unroll
        for (int nf = 0; nf < 4; ++nf) {
            const float* srow = states + ((size_t)n * S_S + sc * 64 + nf * 16 + lrow) * D_D;
            #pragma unroll
            for (int t = 0; t < 4; ++t) {
                bf8 b = load8(srow + t * 32 + lgrp * 8);
                acc[0][nf] = MFMA(a[0][t], b, acc[0][nf]);
                acc[1][nf] = MFMA(a[1][t], b, acc[1][nf]);
            }
        }
        unsigned short* Vout = VTb + (size_t)(n * H_H + h) * D_D * S_S;
        #pragma unroll
        for (int mf = 0; mf < 2; ++mf) {
            #pragma unroll
            for (int r = 0; r < 4; ++r) {
                int drow = w * 32 + mf * 16 + lgrp * 4 + r;
                float bias = bv[h * D_D + drow];
                #pragma unroll
                for (int nf = 0; nf < 4; ++nf) {
                    int scol = sc * 64 + nf * 16 + lrow;
                    Vout[(size_t)drow * S_S + scol] = (unsigned short)f2bf(acc[mf][nf][r] + bias);
                }
            }
        }
    }
}

// ---------------- Kernel C: flash attention (no-max single pass) ----------------
// block = 4 waves, q-tile 128 (32 rows/wave), s-chunks of 64.
// grid: (n*H + h)*16 + qt  -> 1024 blocks
__global__ __launch_bounds__(256) void k_attn(const float* __restrict__ query,
        const unsigned short* __restrict__ Kb, const unsigned short* __restrict__ VTb,
        unsigned short* __restrict__ CTX) {
    __shared__ char smem[49152];
    char* Klds = smem;              // [64][256B] swizzled (K rows s, cols d)
    char* Vlds = smem + 16384;      // [128][128B] swizzled (V^T rows d, cols s)
    const int tid = threadIdx.x;
    const int l = tid & 63, w = tid >> 6;
    const int lrow = l & 15, lgrp = l >> 4;
    char* Plds = smem + 32768 + w * 4096;  // per-wave [32][128B] swizzled

    const int bx = blockIdx.x;
    const int qt = bx & 15;
    const int nh = bx >> 4;
    const int h = nh & 31, n = nh >> 5;
    const int qbase = qt * 128 + w * 32;

    // Q fragments (held in registers across the whole s-loop)
    bf8 qf[2][4];
    #pragma unroll
    for (int mf = 0; mf < 2; ++mf) {
        const float* qp = query + ((size_t)n * L_Q + qbase + mf * 16 + lrow) * D_D;
        #pragma unroll
        for (int t = 0; t < 4; ++t) qf[mf][t] = load8(qp + t * 32 + lgrp * 8);
    }

    f4 acc[2][8];
    #pragma unroll
    for (int mf = 0; mf < 2; ++mf)
        #pragma unroll
        for (int df = 0; df < 8; ++df) acc[mf][df] = (f4)(0.f);
    float rsum[2][4] = {};

    const char* Kg = (const char*)(Kb + (size_t)(n * H_H + h) * S_S * D_D);
    const char* Vg = (const char*)(VTb + (size_t)(n * H_H + h) * D_D * S_S);

    for (int sc2 = 0; sc2 < 32; ++sc2) {
        __syncthreads();   // protect LDS from previous iteration's readers
        // stage K chunk [64][128] bf16, swizzled via pre-swizzled global source
        #pragma unroll
        for (int rnd = 0; rnd < 4; ++rnd) {
            int o = w * 4096 + rnd * 1024 + l * 16;
            int r = o >> 8;
            int b = (o & 255) ^ ((r & 7) << 4);
            async16(Kg + (size_t)(sc2 * 64 + r) * 256 + b, Klds + w * 4096 + rnd * 1024);
        }
        // stage V^T chunk [128][64] bf16
        #pragma unroll
        for (int rnd = 0; rnd < 4; ++rnd) {
            int o = w * 4096 + rnd * 1024 + l * 16;
            int r = o >> 7;
            int b = (o & 127) ^ ((r & 7) << 4);
            async16(Vg + (size_t)r * 4096 + sc2 * 128 + b, Vlds + w * 4096 + rnd * 1024);
        }
        asm volatile("s_waitcnt vmcnt(0)" ::: "memory");
        __syncthreads();

        // QK^T (K folded with scale*log2e) -> exp2 -> P to per-wave LDS
        #pragma unroll
        for (int nf = 0; nf < 4; ++nf) {
            f4 s0 = (f4)(0.f), s1 = (f4)(0.f);
            int srow = nf * 16 + lrow;
            int swz = (srow & 7) << 4;
            #pragma unroll
            for (int t = 0; t < 4; ++t) {
                bf8 b = *(const bf8*)(Klds + srow * 256 + (((t * 32 + lgrp * 8) * 2) ^ swz));
                s0 = MFMA(qf[0][t], b, s0);
                s1 = MFMA(qf[1][t], b, s1);
            }
            int col2 = (nf * 16 + lrow) * 2;
            #pragma unroll
            for (int r = 0; r < 4; ++r) {
                float p0 = __builtin_amdgcn_exp2f(s0[r]);
                float p1 = __builtin_amdgcn_exp2f(s1[r]);
                rsum[0][r] += p0;
                rsum[1][r] += p1;
                int pr0 = lgrp * 4 + r;
                int pr1 = pr0 + 16;
                *(short*)(Plds + pr0 * 128 + (col2 ^ ((pr0 & 7) << 4))) = f2bf(p0);
                *(short*)(Plds + pr1 * 128 + (col2 ^ ((pr1 & 7) << 4))) = f2bf(p1);
            }
        }
        // re-read P as A-fragments (same-wave LDS, no barrier needed)
        bf8 pa[2][2];
        #pragma unroll
        for (int mf = 0; mf < 2; ++mf) {
            int prow = mf * 16 + lrow;
            int swz = (prow & 7) << 4;
            #pragma unroll
            for (int t2 = 0; t2 < 2; ++t2)
                pa[mf][t2] = *(const bf8*)(Plds + prow * 128 + (((t2 * 32 + lgrp * 8) * 2) ^ swz));
        }
        // PV
        #pragma unroll
        for (int df = 0; df < 8; ++df) {
            int drow = df * 16 + lrow;
            int swz = (drow & 7) << 4;
            #pragma unroll
            for (int t2 = 0; t2 < 2; ++t2) {
                bf8 b = *(const bf8*)(Vlds + drow * 128 + (((t2 * 32 + lgrp * 8) * 2) ^ swz));
                acc[0][df] = MFMA(pa[0][t2], b, acc[0][df]);
                acc[1][df] = MFMA(pa[1][t2], b, acc[1][df]);
            }
        }
    }

    // row-sum reduce across the 16 lanes of each group, then normalize + store ctx
    float rinv[2][4];
    #pragma unroll
    for (int mf = 0; mf < 2; ++mf)
        #pragma unroll
        for (int r = 0; r < 4; ++r) {
            float v = rsum[mf][r];
            v += __shfl_xor(v, 1, 64);
            v += __shfl_xor(v, 2, 64);
            v += __shfl_xor(v, 4, 64);
            v += __shfl_xor(v, 8, 64);
            rinv[mf][r] = 1.f / v;
        }
    #pragma unroll
    for (int mf = 0; mf < 2; ++mf) {
        #pragma unroll
        for (int df = 0; df < 8; ++df) {
            int dcol = h * D_D + df * 16 + lrow;
            #pragma unroll
            for (int r = 0; r < 4; ++r) {
                int qrow = qbase + mf * 16 + lgrp * 4 + r;
                CTX[(size_t)(n * L_Q + qrow) * 4096 + dcol] =
                    (unsigned short)f2bf(acc[mf][df][r] * rinv[mf][r]);
            }
        }
    }
}

// ---------------- Kernel E: out = CTX @ Wc + bc ----------------
// 256 blocks x 16 rows; waves split N=128 into 32-col strips; K staged in LDS
__global__ __launch_bounds__(256) void k_out(const unsigned short* __restrict__ CTX,
        const unsigned short* __restrict__ WcT, const float* __restrict__ bc,
        float* __restrict__ out) {
    __shared__ char Alds[4096];   // [16][256B] swizzled
    const int tid = threadIdx.x;
    const int l = tid & 63, w = tid >> 6;
    const int lrow = l & 15, lgrp = l >> 4;
    const int m0 = blockIdx.x * 16;
    const char* Ag = (const char*)(CTX + (size_t)m0 * 4096);

    f4 acc[2];
    acc[0] = (f4)(0.f); acc[1] = (f4)(0.f);
    for (int kc = 0; kc < 32; ++kc) {
        __syncthreads();
        {
            int o = w * 1024 + l * 16;
            int r = o >> 8;
            int b = (o & 255) ^ ((r & 7) << 4);
            async16(Ag + (size_t)r * 8192 + kc * 256 + b, Alds + w * 1024);
        }
        asm volatile("s_waitcnt vmcnt(0)" ::: "memory");
        __syncthreads();
        #pragma unroll
        for (int t = 0; t < 4; ++t) {
            int swz = (lrow & 7) << 4;
            bf8 a = *(const bf8*)(Alds + lrow * 256 + (((t * 32 + lgrp * 8) * 2) ^ swz));
            #pragma unroll
            for (int nf = 0; nf < 2; ++nf) {
                int nc = w * 32 + nf * 16 + lrow;
                bf8 b = *(const bf8*)(WcT + (size_t)nc * 4096 + kc * 128 + t * 32 + lgrp * 8);
                acc[nf] = MFMA(a, b, acc[nf]);
            }
        }
    }
    #pragma unroll
    for (int nf = 0; nf < 2; ++nf) {
        int nc = w * 32 + nf * 16 + lrow;
        float bias = bc[nc];
        #pragma unroll
        for (int r = 0; r < 4; ++r)
            out[(size_t)(m0 + lgrp * 4 + r) * D_D + nc] = acc[nf][r] + bias;
    }
}

extern "C" void kernel_launch(void* const* d_in, const int* in_sizes, int n_in,
                              void* d_out, int out_size, void* d_ws, size_t ws_size,
                              hipStream_t stream) {
    const float* query  = (const float*)d_in[0];
    const float* states = (const float*)d_in[1];
    const float* Wk = (const float*)d_in[2];
    const float* bk = (const float*)d_in[3];
    const float* Wv = (const float*)d_in[4];
    const float* bv = (const float*)d_in[5];
    const float* Wc = (const float*)d_in[6];
    const float* bc = (const float*)d_in[7];
    float* out = (float*)d_out;

    // workspace layout (bf16): Kb 32MB | VTb 32MB | CTX 32MB | WcT 1MB = 101.7MB total
    char* ws = (char*)d_ws;
    unsigned short* Kb  = (unsigned short*)(ws);
    unsigned short* VTb = (unsigned short*)(ws + 33554432);
    unsigned short* CTX = (unsigned short*)(ws + 67108864);
    unsigned short* WcT = (unsigned short*)(ws + 100663296);

    k_wct<<<2048, 256, 0, stream>>>(Wc, WcT);
    dim3 gb(2048, 2);
    k_proj<<<gb, 256, 0, stream>>>(states, Wk, bk, Wv, bv, Kb, VTb);
    k_attn<<<1024, 256, 0, stream>>>(query, Kb, VTb, CTX);
    k_out<<<256, 256, 0, stream>>>(CTX, WcT, bc, out);
}

// Round 2
// 292.010 us; speedup vs baseline: 1.3266x; 1.3266x over previous
//
#include <hip/hip_runtime.h>
#include <hip/hip_bf16.h>

// Problem constants: N=2, L=2048, S=2048, D=128, H=32
#define N_B 2
#define L_Q 2048
#define S_S 2048
#define D_D 128
#define H_H 32
// 1/sqrt(128) * log2(e), folded into K projection so attn uses exp2 directly
#define SCALEK (0.08838834764831845f * 1.4426950408889634f)

typedef __attribute__((ext_vector_type(8))) short bf8;   // 8 bf16 (4 VGPR)
typedef __attribute__((ext_vector_type(4))) float f4;    // 4 f32

#define MFMA(a, b, c) __builtin_amdgcn_mfma_f32_16x16x32_bf16(a, b, c, 0, 0, 0)

__device__ __forceinline__ short f2bf(float x) {
    union { float f; unsigned u; } v; v.f = x;
    unsigned r = v.u + 0x7FFFu + ((v.u >> 16) & 1u);   // RNE
    return (short)(r >> 16);
}

// 8 consecutive f32 from global -> bf16x8 fragment
__device__ __forceinline__ bf8 load8(const float* p) {
    const float4* q = (const float4*)p;
    float4 a = q[0], b = q[1];
    bf8 r;
    r[0] = f2bf(a.x); r[1] = f2bf(a.y); r[2] = f2bf(a.z); r[3] = f2bf(a.w);
    r[4] = f2bf(b.x); r[5] = f2bf(b.y); r[6] = f2bf(b.z); r[7] = f2bf(b.w);
    return r;
}

// async global->LDS, 16B per lane. lds dst must be wave-uniform base (+lane*16 implicit)
__device__ __forceinline__ void async16(const void* g, void* l) {
    __builtin_amdgcn_global_load_lds(
        (const __attribute__((address_space(1))) unsigned*)g,
        (__attribute__((address_space(3))) unsigned*)l, 16, 0, 0);
}

// ---------------- Kernel A: Wc [4096][128] f32 -> WcT [128][4096] bf16 ----------------
__global__ __launch_bounds__(256) void k_wct(const float* __restrict__ Wc,
                                             unsigned short* __restrict__ WcT) {
    int idx = blockIdx.x * 256 + threadIdx.x;   // 524288 total
    int n = idx >> 12;          // 0..127
    int k = idx & 4095;         // 0..4095
    WcT[idx] = (unsigned short)f2bf(Wc[k * D_D + n]);
}

// ---------------- Kernel B: K/V projections ----------------
// job 0: Kb[n][h][s][d]  = (states@Wk + bk) * SCALEK   (bf16, row-major in d)
// job 1: VTb[n][h][d][s] = (states@Wv + bv)            (bf16, transposed)
__global__ __launch_bounds__(256) void k_proj(const float* __restrict__ states,
        const float* __restrict__ Wk, const float* __restrict__ bk,
        const float* __restrict__ Wv, const float* __restrict__ bv,
        unsigned short* __restrict__ Kb, unsigned short* __restrict__ VTb) {
    __shared__ unsigned short WT[128 * 128];    // W^T bf16, swizzled, 32KB
    const int tid = threadIdx.x;
    const int l = tid & 63, w = tid >> 6;
    const int lrow = l & 15, lgrp = l >> 4;
    const int bx = blockIdx.x;                  // (n*H + h)*32 + sc
    const int sc = bx & 31;
    const int nh = bx >> 5;
    const int h = nh & 31, n = nh >> 5;
    const int job = blockIdx.y;

    const float* W = (job ? Wv : Wk) + (size_t)h * (D_D * D_D);
    char* WTc = (char*)WT;
    // stage W^T: coalesced f32 reads, swizzled bf16 LDS writes (WT[d][k], swz byte^((d&7)<<4))
    #pragma unroll
    for (int i = 0; i < 64; ++i) {
        int flat = i * 256 + tid;               // = k*128 + d
        int k = flat >> 7, d = flat & 127;
        short val = f2bf(W[flat]);
        int off = d * 256 + ((k * 2) ^ ((d & 7) << 4));
        *(short*)(WTc + off) = val;
    }
    __syncthreads();

    if (job == 0) {
        // M = 16 s-rows per wave, N = 128 d
        const float* srow = states + ((size_t)n * S_S + sc * 64 + w * 16 + lrow) * D_D;
        bf8 a[4];
        #pragma unroll
        for (int t = 0; t < 4; ++t) a[t] = load8(srow + t * 32 + lgrp * 8);
        f4 acc[8];
        #pragma unroll
        for (int i = 0; i < 8; ++i) acc[i] = (f4)(0.f);
        #pragma unroll
        for (int nf = 0; nf < 8; ++nf) {
            int drow = nf * 16 + lrow;          // B-frag n-index = d
            int swz = (drow & 7) << 4;
            #pragma unroll
            for (int t = 0; t < 4; ++t) {
                bf8 b = *(const bf8*)(WTc + drow * 256 + (((t * 32 + lgrp * 8) * 2) ^ swz));
                acc[nf] = MFMA(a[t], b, acc[nf]);
            }
        }
        unsigned short* Kout = Kb + (size_t)(n * H_H + h) * S_S * D_D;
        #pragma unroll
        for (int nf = 0; nf < 8; ++nf) {
            int dcol = nf * 16 + lrow;
            float bias = bk[h * D_D + dcol];
            #pragma unroll
            for (int r = 0; r < 4; ++r) {
                int srw = sc * 64 + w * 16 + lgrp * 4 + r;
                Kout[(size_t)srw * D_D + dcol] = (unsigned short)f2bf((acc[nf][r] + bias) * SCALEK);
            }
        }
    } else {
        // V^T: M = d (32 rows per wave), N = 64 s. A = Wv^T (from LDS), B = states^T (global)
        bf8 a[2][4];
        #pragma unroll
        for (int mf = 0; mf < 2; ++mf) {
            int drow = w * 32 + mf * 16 + lrow;
            int swz = (drow & 7) << 4;
            #pragma unroll
            for (int t = 0; t < 4; ++t)
                a[mf][t] = *(const bf8*)(WTc + drow * 256 + (((t * 32 + lgrp * 8) * 2) ^ swz));
        }
        f4 acc[2][4];
        #pragma unroll
        for (int mf = 0; mf < 2; ++mf)
            #pragma unroll
            for (int nf = 0; nf < 4; ++nf) acc[mf][nf] = (f4)(0.f);
        #pragma unroll
        for (int nf = 0; nf < 4; ++nf) {
            const float* srow = states + ((size_t)n * S_S + sc * 64 + nf * 16 + lrow) * D_D;
            #pragma unroll
            for (int t = 0; t < 4; ++t) {
                bf8 b = load8(srow + t * 32 + lgrp * 8);
                acc[0][nf] = MFMA(a[0][t], b, acc[0][nf]);
                acc[1][nf] = MFMA(a[1][t], b, acc[1][nf]);
            }
        }
        unsigned short* Vout = VTb + (size_t)(n * H_H + h) * D_D * S_S;
        #pragma unroll
        for (int mf = 0; mf < 2; ++mf) {
            #pragma unroll
            for (int r = 0; r < 4; ++r) {
                int drow = w * 32 + mf * 16 + lgrp * 4 + r;
                float bias = bv[h * D_D + drow];
                #pragma unroll
                for (int nf = 0; nf < 4; ++nf) {
                    int scol = sc * 64 + nf * 16 + lrow;
                    Vout[(size_t)drow * S_S + scol] = (unsigned short)f2bf(acc[mf][nf][r] + bias);
                }
            }
        }
    }
}

// ---------------- Kernel C: flash attention, double-buffered K/V ----------------
// block = 4 waves, q-tile 128 (32 rows/wave), s-chunks of 64, dbuf LDS pipeline.
// grid: 1024 blocks; XCD-swizzled so 16 blocks sharing one head's K/V land on one XCD.
__global__ __launch_bounds__(256) void k_attn(const float* __restrict__ query,
        const unsigned short* __restrict__ Kb, const unsigned short* __restrict__ VTb,
        unsigned short* __restrict__ CTX) {
    // LDS: Kbuf[2] @ 0/16384, Vbuf[2] @ 32768/49152, P @ 65536 (4KB/wave) = 80KB
    __shared__ char smem[81920];
    const int tid = threadIdx.x;
    const int l = tid & 63, w = tid >> 6;
    const int lrow = l & 15, lgrp = l >> 4;
    char* Plds = smem + 65536 + w * 4096;  // per-wave [32][128B] swizzled

    // XCD swizzle: 1024 blocks, 8 XCDs -> 128 consecutive work-ids per XCD
    const int bid = blockIdx.x;
    const int bx = (bid & 7) * 128 + (bid >> 3);
    const int qt = bx & 15;
    const int nh = bx >> 4;
    const int h = nh & 31, n = nh >> 5;
    const int qbase = qt * 128 + w * 32;

    // Q fragments (held in registers across the whole s-loop)
    bf8 qf[2][4];
    #pragma unroll
    for (int mf = 0; mf < 2; ++mf) {
        const float* qp = query + ((size_t)n * L_Q + qbase + mf * 16 + lrow) * D_D;
        #pragma unroll
        for (int t = 0; t < 4; ++t) qf[mf][t] = load8(qp + t * 32 + lgrp * 8);
    }

    f4 acc[2][8];
    #pragma unroll
    for (int mf = 0; mf < 2; ++mf)
        #pragma unroll
        for (int df = 0; df < 8; ++df) acc[mf][df] = (f4)(0.f);
    float rsum[2][4] = {};

    const char* Kg = (const char*)(Kb + (size_t)(n * H_H + h) * S_S * D_D);
    const char* Vg = (const char*)(VTb + (size_t)(n * H_H + h) * D_D * S_S);

    // stage s-chunk `sc2` into buffer `c` (pre-swizzled global source, linear LDS dst)
    auto stage = [&](int c, int sc2) {
        char* Kl = smem + c * 16384;
        char* Vl = smem + 32768 + c * 16384;
        #pragma unroll
        for (int rnd = 0; rnd < 4; ++rnd) {
            int o = w * 4096 + rnd * 1024 + l * 16;
            int r = o >> 8;
            int b = (o & 255) ^ ((r & 7) << 4);
            async16(Kg + (size_t)(sc2 * 64 + r) * 256 + b, Kl + w * 4096 + rnd * 1024);
        }
        #pragma unroll
        for (int rnd = 0; rnd < 4; ++rnd) {
            int o = w * 4096 + rnd * 1024 + l * 16;
            int r = o >> 7;
            int b = (o & 127) ^ ((r & 7) << 4);
            async16(Vg + (size_t)r * 4096 + sc2 * 128 + b, Vl + w * 4096 + rnd * 1024);
        }
    };

    stage(0, 0);
    __syncthreads();          // implicit vmcnt(0): chunk 0 landed
    int cur = 0;

    for (int sc2 = 0; sc2 < 32; ++sc2) {
        // issue next chunk's loads FIRST -> they fly under this iter's compute
        if (sc2 < 31) stage(cur ^ 1, sc2 + 1);
        const char* Klds = smem + cur * 16384;
        const char* Vlds = smem + 32768 + cur * 16384;

        // QK^T (K folded with scale*log2e) -> exp2 -> P to per-wave LDS
        __builtin_amdgcn_s_setprio(1);
        #pragma unroll
        for (int nf = 0; nf < 4; ++nf) {
            f4 s0 = (f4)(0.f), s1 = (f4)(0.f);
            int srow = nf * 16 + lrow;
            int swz = (srow & 7) << 4;
            #pragma unroll
            for (int t = 0; t < 4; ++t) {
                bf8 b = *(const bf8*)(Klds + srow * 256 + (((t * 32 + lgrp * 8) * 2) ^ swz));
                s0 = MFMA(qf[0][t], b, s0);
                s1 = MFMA(qf[1][t], b, s1);
            }
            __builtin_amdgcn_s_setprio(0);
            int col2 = (nf * 16 + lrow) * 2;
            #pragma unroll
            for (int r = 0; r < 4; ++r) {
                float p0 = __builtin_amdgcn_exp2f(s0[r]);
                float p1 = __builtin_amdgcn_exp2f(s1[r]);
                rsum[0][r] += p0;
                rsum[1][r] += p1;
                int pr0 = lgrp * 4 + r;
                int pr1 = pr0 + 16;
                *(short*)(Plds + pr0 * 128 + (col2 ^ ((pr0 & 7) << 4))) = f2bf(p0);
                *(short*)(Plds + pr1 * 128 + (col2 ^ ((pr1 & 7) << 4))) = f2bf(p1);
            }
            __builtin_amdgcn_s_setprio(1);
        }
        // re-read P as A-fragments (same-wave LDS, no barrier needed)
        bf8 pa[2][2];
        #pragma unroll
        for (int mf = 0; mf < 2; ++mf) {
            int prow = mf * 16 + lrow;
            int swz = (prow & 7) << 4;
            #pragma unroll
            for (int t2 = 0; t2 < 2; ++t2)
                pa[mf][t2] = *(const bf8*)(Plds + prow * 128 + (((t2 * 32 + lgrp * 8) * 2) ^ swz));
        }
        // PV
        #pragma unroll
        for (int df = 0; df < 8; ++df) {
            int drow = df * 16 + lrow;
            int swz = (drow & 7) << 4;
            #pragma unroll
            for (int t2 = 0; t2 < 2; ++t2) {
                bf8 b = *(const bf8*)(Vlds + drow * 128 + (((t2 * 32 + lgrp * 8) * 2) ^ swz));
                acc[0][df] = MFMA(pa[0][t2], b, acc[0][df]);
                acc[1][df] = MFMA(pa[1][t2], b, acc[1][df]);
            }
        }
        __builtin_amdgcn_s_setprio(0);

        // single barrier per iter; its implicit vmcnt(0) waits on THIS iter's
        // prefetch (hidden under the compute above), and orders LDS reuse.
        __syncthreads();
        cur ^= 1;
    }

    // row-sum reduce across the 16 lanes of each group, then normalize + store ctx
    float rinv[2][4];
    #pragma unroll
    for (int mf = 0; mf < 2; ++mf)
        #pragma unroll
        for (int r = 0; r < 4; ++r) {
            float v = rsum[mf][r];
            v += __shfl_xor(v, 1, 64);
            v += __shfl_xor(v, 2, 64);
            v += __shfl_xor(v, 4, 64);
            v += __shfl_xor(v, 8, 64);
            rinv[mf][r] = 1.f / v;
        }
    #pragma unroll
    for (int mf = 0; mf < 2; ++mf) {
        #pragma unroll
        for (int df = 0; df < 8; ++df) {
            int dcol = h * D_D + df * 16 + lrow;
            #pragma unroll
            for (int r = 0; r < 4; ++r) {
                int qrow = qbase + mf * 16 + lgrp * 4 + r;
                CTX[(size_t)(n * L_Q + qrow) * 4096 + dcol] =
                    (unsigned short)f2bf(acc[mf][df][r] * rinv[mf][r]);
            }
        }
    }
}

// ---------------- Kernel E: out = CTX @ Wc + bc (dbuf A staging) ----------------
// 256 blocks x 16 rows; waves split N=128 into 32-col strips; A staged in LDS
__global__ __launch_bounds__(256) void k_out(const unsigned short* __restrict__ CTX,
        const unsigned short* __restrict__ WcT, const float* __restrict__ bc,
        float* __restrict__ out) {
    __shared__ char Alds[8192];   // 2 x [16][256B] swizzled
    const int tid = threadIdx.x;
    const int l = tid & 63, w = tid >> 6;
    const int lrow = l & 15, lgrp = l >> 4;
    const int m0 = blockIdx.x * 16;
    const char* Ag = (const char*)(CTX + (size_t)m0 * 4096);

    auto stage = [&](int c, int kc) {
        int o = w * 1024 + l * 16;
        int r = o >> 8;
        int b = (o & 255) ^ ((r & 7) << 4);
        async16(Ag + (size_t)r * 8192 + kc * 256 + b, Alds + c * 4096 + w * 1024);
    };

    f4 acc[2];
    acc[0] = (f4)(0.f); acc[1] = (f4)(0.f);
    stage(0, 0);
    __syncthreads();
    int cur = 0;
    for (int kc = 0; kc < 32; ++kc) {
        if (kc < 31) stage(cur ^ 1, kc + 1);
        const char* Ac = Alds + cur * 4096;
        #pragma unroll
        for (int t = 0; t < 4; ++t) {
            int swz = (lrow & 7) << 4;
            bf8 a = *(const bf8*)(Ac + lrow * 256 + (((t * 32 + lgrp * 8) * 2) ^ swz));
            #pragma unroll
            for (int nf = 0; nf < 2; ++nf) {
                int nc = w * 32 + nf * 16 + lrow;
                bf8 b = *(const bf8*)(WcT + (size_t)nc * 4096 + kc * 128 + t * 32 + lgrp * 8);
                acc[nf] = MFMA(a, b, acc[nf]);
            }
        }
        __syncthreads();
        cur ^= 1;
    }
    #pragma unroll
    for (int nf = 0; nf < 2; ++nf) {
        int nc = w * 32 + nf * 16 + lrow;
        float bias = bc[nc];
        #pragma unroll
        for (int r = 0; r < 4; ++r)
            out[(size_t)(m0 + lgrp * 4 + r) * D_D + nc] = acc[nf][r] + bias;
    }
}

extern "C" void kernel_launch(void* const* d_in, const int* in_sizes, int n_in,
                              void* d_out, int out_size, void* d_ws, size_t ws_size,
                              hipStream_t stream) {
    const float* query  = (const float*)d_in[0];
    const float* states = (const float*)d_in[1];
    const float* Wk = (const float*)d_in[2];
    const float* bk = (const float*)d_in[3];
    const float* Wv = (const float*)d_in[4];
    const float* bv = (const float*)d_in[5];
    const float* Wc = (const float*)d_in[6];
    const float* bc = (const float*)d_in[7];
    float* out = (float*)d_out;

    // workspace layout (bf16): Kb 32MB | VTb 32MB | CTX 32MB | WcT 1MB = 101.7MB total
    char* ws = (char*)d_ws;
    unsigned short* Kb  = (unsigned short*)(ws);
    unsigned short* VTb = (unsigned short*)(ws + 33554432);
    unsigned short* CTX = (unsigned short*)(ws + 67108864);
    unsigned short* WcT = (unsigned short*)(ws + 100663296);

    k_wct<<<2048, 256, 0, stream>>>(Wc, WcT);
    dim3 gb(2048, 2);
    k_proj<<<gb, 256, 0, stream>>>(states, Wk, bk, Wv, bv, Kb, VTb);
    k_attn<<<1024, 256, 0, stream>>>(query, Kb, VTb, CTX);
    k_out<<<256, 256, 0, stream>>>(CTX, WcT, bc, out);
}